// Round 1
// baseline (115.027 us; speedup 1.0000x reference)
//
#include <hip/hip_runtime.h>
#include <math.h>

// Problem constants (from setup_inputs): B=32, S=4096, H=768.
constexpr int B = 32;
constexpr int S = 4096;
constexpr int H = 768;

constexpr int BLOCKS_PER_BATCH = 32;                       // partials per batch
constexpr int ROWS_PER_BLOCK   = S / BLOCKS_PER_BATCH;     // 128
constexpr int WAVES_PER_BLOCK  = 4;                        // 256 threads
constexpr int ROWS_PER_WAVE    = ROWS_PER_BLOCK / WAVES_PER_BLOCK; // 32
constexpr int NPART            = B * BLOCKS_PER_BATCH;     // 1024

// ---------------------------------------------------------------------------
// Kernel 1: fused score + online-softmax pooling, one streaming pass over
// hidden_states. Each wave handles 32 contiguous rows independently (no
// cross-wave sync in the hot loop). 4 waves/block combine partials in LDS.
// ---------------------------------------------------------------------------
__global__ __launch_bounds__(256)
void pool_partial(const float* __restrict__ hs,
                  const int*   __restrict__ mask,
                  const int*   __restrict__ boost,
                  const float* __restrict__ attn_w,
                  const float* __restrict__ attn_b,
                  float* __restrict__ pm, float* __restrict__ pl,
                  float* __restrict__ pc)
{
    const int blk  = blockIdx.x;                 // 0..1023
    const int b    = blk >> 5;                   // batch
    const int kb   = blk & (BLOCKS_PER_BATCH - 1);
    const int tid  = threadIdx.x;
    const int w    = tid >> 6;                   // wave id in block
    const int lane = tid & 63;
    const int s0   = kb * ROWS_PER_BLOCK + w * ROWS_PER_WAVE;

    // lane owns columns {4l..4l+3, 256+4l.., 512+4l..}
    const float4 w0 = *reinterpret_cast<const float4*>(attn_w +       4 * lane);
    const float4 w1 = *reinterpret_cast<const float4*>(attn_w + 256 + 4 * lane);
    const float4 w2 = *reinterpret_cast<const float4*>(attn_w + 512 + 4 * lane);
    const float bias = attn_b[0];

    float m = -INFINITY, l = 0.0f;
    float c[12];
#pragma unroll
    for (int j = 0; j < 12; ++j) c[j] = 0.0f;

    const float* base = hs + (size_t)b * S * H;
    const int*   mrow = mask  + (size_t)b * S;
    const int*   brow = boost + (size_t)b * S;

    for (int r = 0; r < ROWS_PER_WAVE; ++r) {
        const int s = s0 + r;
        const float4* row = reinterpret_cast<const float4*>(base + (size_t)s * H);
        const float4 v0 = row[lane];
        const float4 v1 = row[64  + lane];
        const float4 v2 = row[128 + lane];

        float d = v0.x * w0.x + v0.y * w0.y + v0.z * w0.z + v0.w * w0.w
                + v1.x * w1.x + v1.y * w1.y + v1.z * w1.z + v1.w * w1.w
                + v2.x * w2.x + v2.y * w2.y + v2.z * w2.z + v2.w * w2.w;
#pragma unroll
        for (int off = 32; off > 0; off >>= 1) d += __shfl_xor(d, off, 64);

        const int   mk   = mrow[s];
        const float mult = 1.0f + 2.0f * (float)brow[s];
        const float score = (d + bias) * mult;

        if (mk != 0) {
            const float mn = fmaxf(m, score);
            const float sc = __expf(m - mn);       // 0 when m == -inf
            const float p  = __expf(score - mn);
            l = l * sc + p;
            c[0]  = c[0]  * sc + p * v0.x;  c[1]  = c[1]  * sc + p * v0.y;
            c[2]  = c[2]  * sc + p * v0.z;  c[3]  = c[3]  * sc + p * v0.w;
            c[4]  = c[4]  * sc + p * v1.x;  c[5]  = c[5]  * sc + p * v1.y;
            c[6]  = c[6]  * sc + p * v1.z;  c[7]  = c[7]  * sc + p * v1.w;
            c[8]  = c[8]  * sc + p * v2.x;  c[9]  = c[9]  * sc + p * v2.y;
            c[10] = c[10] * sc + p * v2.z;  c[11] = c[11] * sc + p * v2.w;
            m = mn;
        }
    }

    // intra-block combine (4 waves -> 1 partial)
    __shared__ float sm[WAVES_PER_BLOCK], sl[WAVES_PER_BLOCK];
    __shared__ float scmb[WAVES_PER_BLOCK][H];
#pragma unroll
    for (int j = 0; j < 4; ++j) {
        scmb[w][4 * lane + j]       = c[j];
        scmb[w][256 + 4 * lane + j] = c[4 + j];
        scmb[w][512 + 4 * lane + j] = c[8 + j];
    }
    if (lane == 0) { sm[w] = m; sl[w] = l; }
    __syncthreads();

    const float M  = fmaxf(fmaxf(sm[0], sm[1]), fmaxf(sm[2], sm[3]));
    const float e0 = __expf(sm[0] - M), e1 = __expf(sm[1] - M);
    const float e2 = __expf(sm[2] - M), e3 = __expf(sm[3] - M);
    if (tid == 0) {
        pm[blk] = M;
        pl[blk] = sl[0] * e0 + sl[1] * e1 + sl[2] * e2 + sl[3] * e3;
    }
#pragma unroll
    for (int q = 0; q < 3; ++q) {
        const int h = tid + q * 256;
        pc[(size_t)blk * H + h] =
            scmb[0][h] * e0 + scmb[1][h] * e1 + scmb[2][h] * e2 + scmb[3][h] * e3;
    }
}

// ---------------------------------------------------------------------------
// Kernel 2: combine 32 partials per batch -> context[32][768]
// ---------------------------------------------------------------------------
__global__ __launch_bounds__(256)
void pool_combine(const float* __restrict__ pm, const float* __restrict__ pl,
                  const float* __restrict__ pc, float* __restrict__ context)
{
    const int b   = blockIdx.x;
    const int tid = threadIdx.x;
    __shared__ float ss[BLOCKS_PER_BATCH];

    float M = -INFINITY;
    for (int i = 0; i < BLOCKS_PER_BATCH; ++i)
        M = fmaxf(M, pm[b * BLOCKS_PER_BATCH + i]);
    if (tid < BLOCKS_PER_BATCH)
        ss[tid] = __expf(pm[b * BLOCKS_PER_BATCH + tid] - M);
    __syncthreads();

    float L = 0.0f;
    for (int i = 0; i < BLOCKS_PER_BATCH; ++i)
        L += pl[b * BLOCKS_PER_BATCH + i] * ss[i];
    const float invL = 1.0f / L;

#pragma unroll
    for (int q = 0; q < 3; ++q) {
        const int h = tid + q * 256;
        float acc = 0.0f;
        for (int i = 0; i < BLOCKS_PER_BATCH; ++i)
            acc += pc[((size_t)b * BLOCKS_PER_BATCH + i) * H + h] * ss[i];
        context[b * H + h] = acc * invL;
    }
}

// ---------------------------------------------------------------------------
// Kernel 3: BatchNorm1d (training-mode batch stats, biased variance, eps=1e-5)
// ---------------------------------------------------------------------------
__global__ __launch_bounds__(256)
void batchnorm_k(const float* __restrict__ context,
                 const float* __restrict__ gamma, const float* __restrict__ beta,
                 float* __restrict__ chat)
{
    const int h = blockIdx.x * 256 + threadIdx.x;  // 0..767
    float x[B];
    float mean = 0.0f;
#pragma unroll
    for (int b = 0; b < B; ++b) { x[b] = context[b * H + h]; mean += x[b]; }
    mean *= (1.0f / B);
    float var = 0.0f;
#pragma unroll
    for (int b = 0; b < B; ++b) { const float d = x[b] - mean; var += d * d; }
    var *= (1.0f / B);
    const float inv = rsqrtf(var + 1e-5f);
    const float g = gamma[h], be = beta[h];
#pragma unroll
    for (int b = 0; b < B; ++b)
        chat[b * H + h] = (x[b] - mean) * inv * g + be;
}

// ---------------------------------------------------------------------------
// Kernel 4: out = relu(chat @ fc_w.T + fc_b + chat)
// ---------------------------------------------------------------------------
__global__ __launch_bounds__(256)
void fc_relu_k(const float* __restrict__ chat, const float* __restrict__ fcw,
               const float* __restrict__ fcb, float* __restrict__ out)
{
    const int i = blockIdx.x * 256 + threadIdx.x;  // output column
    const int b = blockIdx.y;                      // batch row
    const float* cb = chat + (size_t)b * H;
    const float4* wr  = reinterpret_cast<const float4*>(fcw + (size_t)i * H);
    const float4* cbv = reinterpret_cast<const float4*>(cb);

    float acc = fcb[i];
#pragma unroll 4
    for (int hq = 0; hq < H / 4; ++hq) {
        const float4 wv = wr[hq];
        const float4 cv = cbv[hq];
        acc += wv.x * cv.x + wv.y * cv.y + wv.z * cv.z + wv.w * cv.w;
    }
    acc += cb[i];
    out[(size_t)b * H + i] = fmaxf(acc, 0.0f);
}

// ---------------------------------------------------------------------------
extern "C" void kernel_launch(void* const* d_in, const int* in_sizes, int n_in,
                              void* d_out, int out_size, void* d_ws, size_t ws_size,
                              hipStream_t stream)
{
    const float* hs     = (const float*)d_in[0];
    const int*   mask   = (const int*)d_in[1];
    const int*   boost  = (const int*)d_in[2];
    const float* attn_w = (const float*)d_in[3];
    const float* attn_b = (const float*)d_in[4];
    const float* fc_w   = (const float*)d_in[5];
    const float* fc_b   = (const float*)d_in[6];
    const float* gamma  = (const float*)d_in[7];
    const float* beta   = (const float*)d_in[8];
    float* out = (float*)d_out;

    float* ws      = (float*)d_ws;
    float* pm      = ws;                          // [1024]
    float* pl      = pm + NPART;                  // [1024]
    float* pc      = pl + NPART;                  // [1024][768]
    float* context = pc + (size_t)NPART * H;      // [32][768]
    float* chat    = context + B * H;             // [32][768]
    // total: ~3.35 MB of d_ws

    pool_partial<<<dim3(NPART), 256, 0, stream>>>(hs, mask, boost, attn_w, attn_b,
                                                  pm, pl, pc);
    pool_combine<<<dim3(B), 256, 0, stream>>>(pm, pl, pc, context);
    batchnorm_k<<<dim3(H / 256), 256, 0, stream>>>(context, gamma, beta, chat);
    fc_relu_k<<<dim3(H / 256, B), 256, 0, stream>>>(chat, fc_w, fc_b, out);
}